// Round 2
// baseline (4493.514 us; speedup 1.0000x reference)
//
#include <hip/hip_runtime.h>

// ScoreNetGNN: B=50000 graphs x 7 nodes, fully-connected (42 edges/graph).
// One wave (64 lanes) per graph; lane = feature channel. Weights staged to LDS
// (fp32) per phase, activations in registers, broadcasts via v_readlane.
// EdgeConv first-linear decomposed: [xi, xj-xi]@W = (r_i - q_i) + q_j.
// Runtime dtype probe (bf16 vs f32) because the harness's tensor dtype is
// ambiguous: detect_kernel writes a flag into d_ws; main kernel branches
// uniformly on it for loads/stores only (hot loops are all-f32).

#define NB 50000

typedef unsigned short u16;

__device__ __forceinline__ float b2f(u16 u) {
    return __uint_as_float(((unsigned int)u) << 16);
}
__device__ __forceinline__ u16 f2b(float f) {
    unsigned int u = __float_as_uint(f);
    u += 0x7FFFu + ((u >> 16) & 1u);   // RNE
    return (u16)(u >> 16);
}
__device__ __forceinline__ float bcast(float v, int l) {
    return __uint_as_float(__builtin_amdgcn_readlane(__float_as_uint(v), l));
}
__device__ __forceinline__ float ldf(const void* p, int i, int fm) {
    return fm ? ((const float*)p)[i] : b2f(((const u16*)p)[i]);
}
__device__ __forceinline__ void stage(const void* src, float* dst, int n, int fm) {
    if (fm) {
        const float* s = (const float*)src;
        for (int i = threadIdx.x; i < n; i += 256) dst[i] = s[i];
    } else {
        const u16* s = (const u16*)src;
        for (int i = threadIdx.x; i < n; i += 256) dst[i] = b2f(s[i]);
    }
}

// Decide whether float tensors are bf16 (flag=0) or f32 (flag=1) by decoding
// the first 32 u16s of t as bf16: genuine bf16 t values all lie in (4e-4,1.002];
// f32-as-u16 low halves are ~random bit patterns and fail with certainty.
__global__ void detect_kernel(const void* t, int* flag) {
    if (threadIdx.x == 0) {
        const u16* p = (const u16*)t;
        int ok = 1;
        for (int i = 0; i < 32; ++i) {
            float v = b2f(p[i]);
            if (!(v > 4.0e-4f && v <= 1.002f)) ok = 0;
        }
        *flag = ok ? 0 : 1;   // 1 => tensors are f32
    }
}

__global__ __launch_bounds__(256) void gnn_kernel(
    const void* __restrict__ omega, const void* __restrict__ tt, const void* __restrict__ Wf,
    const void* __restrict__ wi1, const void* __restrict__ bi1,
    const void* __restrict__ wi2, const void* __restrict__ bi2,
    const void* __restrict__ wt,  const void* __restrict__ bt,
    const void* __restrict__ w1a, const void* __restrict__ b1a,
    const void* __restrict__ w1b, const void* __restrict__ b1b,
    const void* __restrict__ w2a, const void* __restrict__ b2a,
    const void* __restrict__ w2b, const void* __restrict__ b2b,
    const void* __restrict__ w3a, const void* __restrict__ b3a,
    const void* __restrict__ w3b, const void* __restrict__ b3b,
    void* __restrict__ out, const int* __restrict__ flag)
{
    __shared__ float wbuf[12288];              // staged weights (max: w2a/w3a 192x64)
    const int fm   = *flag;                    // uniform: 1 = f32 tensors, 0 = bf16
    const int lane = threadIdx.x & 63;
    const int wav  = threadIdx.x >> 6;
    const int g    = blockIdx.x * 4 + wav;     // graph id, grid covers exactly 50000
    const int base = g * 7;                    // first node of this graph

    // ---------------- Phase A: wi2 + wt staged ----------------
    stage(wi2, wbuf, 4096, fm);
    stage(wt,  wbuf + 4096, 1024, fm);
    __syncthreads();

    // init MLP: h1 = relu(omega@wi1+bi1);  x0 = h1@wi2 + bi2  (no outer relu)
    float omv = 0.f;
    if (lane < 21) omv = ldf(omega, base * 3 + lane, fm);   // 7 nodes x 3 coords
    float vwi10 = ldf(wi1, lane, fm);
    float vwi11 = ldf(wi1, 64 + lane, fm);
    float vwi12 = ldf(wi1, 128 + lane, fm);
    float vbi1 = ldf(bi1, lane, fm);
    float vbi2 = ldf(bi2, lane, fm);
    float h1[7];
#pragma unroll
    for (int k = 0; k < 7; ++k) {
        float a0 = bcast(omv, 3 * k), a1 = bcast(omv, 3 * k + 1), a2 = bcast(omv, 3 * k + 2);
        h1[k] = fmaxf(fmaf(a0, vwi10, fmaf(a1, vwi11, fmaf(a2, vwi12, vbi1))), 0.f);
    }
    float xh[7];   // current 64-dim node feature, lane = channel
#pragma unroll
    for (int k = 0; k < 7; ++k) {
        float y0 = vbi2, y1 = 0.f, y2 = 0.f, y3 = 0.f;
#pragma unroll 1
        for (int c = 0; c < 64; c += 4) {
            y0 = fmaf(bcast(h1[k], c    ), wbuf[(c    ) * 64 + lane], y0);
            y1 = fmaf(bcast(h1[k], c + 1), wbuf[(c + 1) * 64 + lane], y1);
            y2 = fmaf(bcast(h1[k], c + 2), wbuf[(c + 2) * 64 + lane], y2);
            y3 = fmaf(bcast(h1[k], c + 3), wbuf[(c + 3) * 64 + lane], y3);
        }
        xh[k] = (y0 + y1) + (y2 + y3);
    }

    // time embedding per node: NOTE tile-bug -> node n uses t[n % B]
    float vwf = ldf(Wf, lane & 15, fm) * 6.283185307179586f;
    float vbt = ldf(bt, lane & 31, fm);
    float xs[7];   // valid in lanes 0..31 (dup in 32..63)
#pragma unroll
    for (int k = 0; k < 7; ++k) {
        int ti = (base + k) % NB;
        float tv = ldf(tt, ti, fm);
        float pj = tv * vwf;
        float sv = sinf(pj), cv = cosf(pj);
        float remb = fmaxf((lane < 16) ? sv : cv, 0.f);   // relu(emb), emb=[sin|cos]
        float y0 = vbt, y1 = 0.f;
#pragma unroll 1
        for (int c = 0; c < 32; c += 2) {
            y0 = fmaf(bcast(remb, c    ), wbuf[4096 + (c    ) * 32 + (lane & 31)], y0);
            y1 = fmaf(bcast(remb, c + 1), wbuf[4096 + (c + 1) * 32 + (lane & 31)], y1);
        }
        xs[k] = fmaxf(y0 + y1, 0.f);
    }

    float pp[7], qq[7], xnew[7];

    // ---------------- Layer 1 ----------------
    __syncthreads();
    stage(w1a, wbuf, 8192, fm);                // (128,64): rows 0..63 xi, 64..127 (xj-xi)
    __syncthreads();
    {
        float vb = ldf(b1a, lane, fm);
#pragma unroll
        for (int k = 0; k < 7; ++k) {
            float r0 = vb, r1 = 0.f, q0 = 0.f, q1 = 0.f;
#pragma unroll 1
            for (int c = 0; c < 64; c += 2) {
                float s0 = bcast(xh[k], c), s1 = bcast(xh[k], c + 1);
                r0 = fmaf(s0, wbuf[(c     ) * 64 + lane], r0);
                r1 = fmaf(s1, wbuf[(c + 1 ) * 64 + lane], r1);
                q0 = fmaf(s0, wbuf[(64 + c) * 64 + lane], q0);
                q1 = fmaf(s1, wbuf[(65 + c) * 64 + lane], q1);
            }
            qq[k] = q0 + q1;
            pp[k] = (r0 + r1) - qq[k];         // xi@Wtop + b - xi@Wbot
        }
    }
    __syncthreads();
    stage(w1b, wbuf, 4096, fm);
    __syncthreads();
    {
        float vb = ldf(b1b, lane, fm);
#pragma unroll
        for (int i = 0; i < 7; ++i) {
            float mx = -3.0e38f;
#pragma unroll
            for (int jj = 0; jj < 6; ++jj) {
                int j = jj + (jj >= i);
                float hv = fmaxf(pp[i] + qq[j], 0.f);
                float y0 = vb, y1 = 0.f, y2 = 0.f, y3 = 0.f;
#pragma unroll 1
                for (int c = 0; c < 64; c += 4) {
                    y0 = fmaf(bcast(hv, c    ), wbuf[(c    ) * 64 + lane], y0);
                    y1 = fmaf(bcast(hv, c + 1), wbuf[(c + 1) * 64 + lane], y1);
                    y2 = fmaf(bcast(hv, c + 2), wbuf[(c + 2) * 64 + lane], y2);
                    y3 = fmaf(bcast(hv, c + 3), wbuf[(c + 3) * 64 + lane], y3);
                }
                mx = fmaxf(mx, (y0 + y1) + (y2 + y3));
            }
            xnew[i] = fmaxf(mx, 0.f);          // relu(edge_conv)
        }
#pragma unroll
        for (int k = 0; k < 7; ++k) xh[k] = xnew[k];
    }

    // ---------------- Layer 2 ---------------- input = [xh(64) | xs(32)]
    __syncthreads();
    stage(w2a, wbuf, 12288, fm);               // (192,64)
    __syncthreads();
    {
        float vb = ldf(b2a, lane, fm);
#pragma unroll
        for (int k = 0; k < 7; ++k) {
            float r0 = vb, r1 = 0.f, q0 = 0.f, q1 = 0.f;
#pragma unroll 1
            for (int c = 0; c < 64; c += 2) {
                float s0 = bcast(xh[k], c), s1 = bcast(xh[k], c + 1);
                r0 = fmaf(s0, wbuf[(c      ) * 64 + lane], r0);
                r1 = fmaf(s1, wbuf[(c + 1  ) * 64 + lane], r1);
                q0 = fmaf(s0, wbuf[(96 + c ) * 64 + lane], q0);
                q1 = fmaf(s1, wbuf[(97 + c ) * 64 + lane], q1);
            }
#pragma unroll 1
            for (int c = 0; c < 32; c += 2) {
                float s0 = bcast(xs[k], c), s1 = bcast(xs[k], c + 1);
                r0 = fmaf(s0, wbuf[(64 + c ) * 64 + lane], r0);
                r1 = fmaf(s1, wbuf[(65 + c ) * 64 + lane], r1);
                q0 = fmaf(s0, wbuf[(160 + c) * 64 + lane], q0);
                q1 = fmaf(s1, wbuf[(161 + c) * 64 + lane], q1);
            }
            qq[k] = q0 + q1;
            pp[k] = (r0 + r1) - qq[k];
        }
    }
    __syncthreads();
    stage(w2b, wbuf, 4096, fm);
    __syncthreads();
    {
        float vb = ldf(b2b, lane, fm);
#pragma unroll
        for (int i = 0; i < 7; ++i) {
            float mx = -3.0e38f;
#pragma unroll
            for (int jj = 0; jj < 6; ++jj) {
                int j = jj + (jj >= i);
                float hv = fmaxf(pp[i] + qq[j], 0.f);
                float y0 = vb, y1 = 0.f, y2 = 0.f, y3 = 0.f;
#pragma unroll 1
                for (int c = 0; c < 64; c += 4) {
                    y0 = fmaf(bcast(hv, c    ), wbuf[(c    ) * 64 + lane], y0);
                    y1 = fmaf(bcast(hv, c + 1), wbuf[(c + 1) * 64 + lane], y1);
                    y2 = fmaf(bcast(hv, c + 2), wbuf[(c + 2) * 64 + lane], y2);
                    y3 = fmaf(bcast(hv, c + 3), wbuf[(c + 3) * 64 + lane], y3);
                }
                mx = fmaxf(mx, (y0 + y1) + (y2 + y3));
            }
            xnew[i] = fmaxf(mx, 0.f);
        }
#pragma unroll
        for (int k = 0; k < 7; ++k) xh[k] = xnew[k];
    }

    // ---------------- Layer 3 ---------------- out = edge_conv (no relu) / (std+1e-7)
    __syncthreads();
    stage(w3a, wbuf, 12288, fm);
    __syncthreads();
    {
        float vb = ldf(b3a, lane, fm);
#pragma unroll
        for (int k = 0; k < 7; ++k) {
            float r0 = vb, r1 = 0.f, q0 = 0.f, q1 = 0.f;
#pragma unroll 1
            for (int c = 0; c < 64; c += 2) {
                float s0 = bcast(xh[k], c), s1 = bcast(xh[k], c + 1);
                r0 = fmaf(s0, wbuf[(c      ) * 64 + lane], r0);
                r1 = fmaf(s1, wbuf[(c + 1  ) * 64 + lane], r1);
                q0 = fmaf(s0, wbuf[(96 + c ) * 64 + lane], q0);
                q1 = fmaf(s1, wbuf[(97 + c ) * 64 + lane], q1);
            }
#pragma unroll 1
            for (int c = 0; c < 32; c += 2) {
                float s0 = bcast(xs[k], c), s1 = bcast(xs[k], c + 1);
                r0 = fmaf(s0, wbuf[(64 + c ) * 64 + lane], r0);
                r1 = fmaf(s1, wbuf[(65 + c ) * 64 + lane], r1);
                q0 = fmaf(s0, wbuf[(160 + c) * 64 + lane], q0);
                q1 = fmaf(s1, wbuf[(161 + c) * 64 + lane], q1);
            }
            qq[k] = q0 + q1;
            pp[k] = (r0 + r1) - qq[k];
        }
    }
    // w3b (64,3) per-lane rows; second linear via per-lane product + wave reduce
    {
        float w3b0 = ldf(w3b, lane * 3, fm);
        float w3b1 = ldf(w3b, lane * 3 + 1, fm);
        float w3b2 = ldf(w3b, lane * 3 + 2, fm);
        float vb0 = ldf(b3b, 0, fm), vb1 = ldf(b3b, 1, fm), vb2 = ldf(b3b, 2, fm);

        // std uses t[n // 7] == t[g] (repeat_interleave)
        float tg = ldf(tt, g, fm);
        // std = sqrt((25^(2t)-1)/(2 ln 25)); 2*log2(25)=9.287712379549448, 1/(2 ln25)=0.15533740282828987
        float stdv = sqrtf((exp2f(tg * 9.287712379549448f) - 1.0f) * 0.15533740282828987f);
        float inv = 1.0f / (stdv + 1e-7f);

#pragma unroll
        for (int i = 0; i < 7; ++i) {
            float m0 = -3.0e38f, m1 = -3.0e38f, m2 = -3.0e38f;
#pragma unroll
            for (int jj = 0; jj < 6; ++jj) {
                int j = jj + (jj >= i);
                float hv = fmaxf(pp[i] + qq[j], 0.f);
                float s0 = hv * w3b0, s1 = hv * w3b1, s2 = hv * w3b2;
#pragma unroll
                for (int d = 1; d < 64; d <<= 1) {
                    s0 += __shfl_xor(s0, d, 64);
                    s1 += __shfl_xor(s1, d, 64);
                    s2 += __shfl_xor(s2, d, 64);
                }
                m0 = fmaxf(m0, s0); m1 = fmaxf(m1, s1); m2 = fmaxf(m2, s2);
            }
            m0 += vb0; m1 += vb1; m2 += vb2;
            if (lane < 3) {
                float v = ((lane == 0) ? m0 : (lane == 1) ? m1 : m2) * inv;
                int oi = (base + i) * 3 + lane;
                if (fm) ((float*)out)[oi] = v;
                else    ((u16*)out)[oi]  = f2b(v);
            }
        }
    }
}

extern "C" void kernel_launch(void* const* d_in, const int* in_sizes, int n_in,
                              void* d_out, int out_size, void* d_ws, size_t ws_size,
                              hipStream_t stream) {
    const void* omega = d_in[0];
    // d_in[1] = edge_index (structure is fixed fully-connected per graph; unused)
    const void* tt  = d_in[2];
    // d_in[3] = num_objs (== 7, hardcoded)
    const void* Wf  = d_in[4];
    const void* wi1 = d_in[5];
    const void* bi1 = d_in[6];
    const void* wi2 = d_in[7];
    const void* bi2 = d_in[8];
    const void* wt  = d_in[9];
    const void* bt  = d_in[10];
    const void* w1a = d_in[11];
    const void* b1a = d_in[12];
    const void* w1b = d_in[13];
    const void* b1b = d_in[14];
    const void* w2a = d_in[15];
    const void* b2a = d_in[16];
    const void* w2b = d_in[17];
    const void* b2b = d_in[18];
    const void* w3a = d_in[19];
    const void* b3a = d_in[20];
    const void* w3b = d_in[21];
    const void* b3b = d_in[22];

    int* flag = (int*)d_ws;
    detect_kernel<<<dim3(1), dim3(64), 0, stream>>>(tt, flag);
    gnn_kernel<<<dim3(12500), dim3(256), 0, stream>>>(
        omega, tt, Wf, wi1, bi1, wi2, bi2, wt, bt,
        w1a, b1a, w1b, b1b, w2a, b2a, w2b, b2b, w3a, b3a, w3b, b3b,
        d_out, flag);
}

// Round 3
// 3347.079 us; speedup vs baseline: 1.3425x; 1.3425x over previous
//
#include <hip/hip_runtime.h>

// ScoreNetGNN: B=50000 graphs x 7 nodes, fully-connected (42 edges/graph).
// One wave (64 lanes) per graph; lane = feature channel. Weights staged to LDS
// (fp32) per phase, activations in registers, broadcasts via v_readlane.
// EdgeConv first-linear decomposed: [xi, xj-xi]@W = (r_i - q_i) + q_j.
// R2: LDS cut 48KB->32KB (chunked w2a/w3a staging) to double occupancy;
// float4 staging; unroll-2 inner loops for more outstanding ds_reads.
// Runtime dtype probe retained (bench confirmed f32 via WRITE_SIZE, but probe
// costs ~2us and keeps the bf16 fallback alive).

#define NB 50000

typedef unsigned short u16;

__device__ __forceinline__ float b2f(u16 u) {
    return __uint_as_float(((unsigned int)u) << 16);
}
__device__ __forceinline__ u16 f2b(float f) {
    unsigned int u = __float_as_uint(f);
    u += 0x7FFFu + ((u >> 16) & 1u);   // RNE
    return (u16)(u >> 16);
}
__device__ __forceinline__ float bcast(float v, int l) {
    return __uint_as_float(__builtin_amdgcn_readlane(__float_as_uint(v), l));
}
__device__ __forceinline__ float ldf(const void* p, int i, int fm) {
    return fm ? ((const float*)p)[i] : b2f(((const u16*)p)[i]);
}
// stage n floats (n%4==0) from element offset `off` of src into LDS dst
__device__ __forceinline__ void stage(const void* src, int off, float* dst, int n, int fm) {
    if (fm) {
        const float4* s = (const float4*)((const float*)src + off);
        float4* d = (float4*)dst;
        for (int i = threadIdx.x; i < (n >> 2); i += 256) d[i] = s[i];
    } else {
        const u16* s = (const u16*)src + off;
        for (int i = threadIdx.x; i < n; i += 256) dst[i] = b2f(s[i]);
    }
}

// Decide whether float tensors are bf16 (flag=0) or f32 (flag=1) by decoding
// the first 32 u16s of t as bf16: genuine bf16 t values all lie in (4e-4,1.002];
// f32-as-u16 low halves are ~random bit patterns and fail with certainty.
__global__ void detect_kernel(const void* t, int* flag) {
    if (threadIdx.x == 0) {
        const u16* p = (const u16*)t;
        int ok = 1;
        for (int i = 0; i < 32; ++i) {
            float v = b2f(p[i]);
            if (!(v > 4.0e-4f && v <= 1.002f)) ok = 0;
        }
        *flag = ok ? 0 : 1;   // 1 => tensors are f32
    }
}

__global__ __launch_bounds__(256, 4) void gnn_kernel(
    const void* __restrict__ omega, const void* __restrict__ tt, const void* __restrict__ Wf,
    const void* __restrict__ wi1, const void* __restrict__ bi1,
    const void* __restrict__ wi2, const void* __restrict__ bi2,
    const void* __restrict__ wt,  const void* __restrict__ bt,
    const void* __restrict__ w1a, const void* __restrict__ b1a,
    const void* __restrict__ w1b, const void* __restrict__ b1b,
    const void* __restrict__ w2a, const void* __restrict__ b2a,
    const void* __restrict__ w2b, const void* __restrict__ b2b,
    const void* __restrict__ w3a, const void* __restrict__ b3a,
    const void* __restrict__ w3b, const void* __restrict__ b3b,
    void* __restrict__ out, const int* __restrict__ flag)
{
    __shared__ __align__(16) float wbuf[8192];   // 32 KB: 4 blocks/CU resident
    const int fm   = *flag;                      // uniform: 1 = f32 tensors, 0 = bf16
    const int lane = threadIdx.x & 63;
    const int wav  = threadIdx.x >> 6;
    const int g    = blockIdx.x * 4 + wav;       // graph id, grid covers exactly 50000
    const int base = g * 7;                      // first node of this graph

    // ---------------- Phase A: wi2 + wt staged ----------------
    stage(wi2, 0, wbuf, 4096, fm);
    stage(wt,  0, wbuf + 4096, 1024, fm);
    __syncthreads();

    // init MLP: h1 = relu(omega@wi1+bi1);  x0 = h1@wi2 + bi2  (no outer relu)
    float omv = 0.f;
    if (lane < 21) omv = ldf(omega, base * 3 + lane, fm);   // 7 nodes x 3 coords
    float vwi10 = ldf(wi1, lane, fm);
    float vwi11 = ldf(wi1, 64 + lane, fm);
    float vwi12 = ldf(wi1, 128 + lane, fm);
    float vbi1 = ldf(bi1, lane, fm);
    float vbi2 = ldf(bi2, lane, fm);
    float h1[7];
#pragma unroll
    for (int k = 0; k < 7; ++k) {
        float a0 = bcast(omv, 3 * k), a1 = bcast(omv, 3 * k + 1), a2 = bcast(omv, 3 * k + 2);
        h1[k] = fmaxf(fmaf(a0, vwi10, fmaf(a1, vwi11, fmaf(a2, vwi12, vbi1))), 0.f);
    }
    float xh[7];   // current 64-dim node feature, lane = channel
#pragma unroll
    for (int k = 0; k < 7; ++k) {
        float y0 = vbi2, y1 = 0.f, y2 = 0.f, y3 = 0.f;
#pragma unroll 2
        for (int c = 0; c < 64; c += 4) {
            y0 = fmaf(bcast(h1[k], c    ), wbuf[(c    ) * 64 + lane], y0);
            y1 = fmaf(bcast(h1[k], c + 1), wbuf[(c + 1) * 64 + lane], y1);
            y2 = fmaf(bcast(h1[k], c + 2), wbuf[(c + 2) * 64 + lane], y2);
            y3 = fmaf(bcast(h1[k], c + 3), wbuf[(c + 3) * 64 + lane], y3);
        }
        xh[k] = (y0 + y1) + (y2 + y3);
    }

    // time embedding per node: NOTE tile-bug -> node n uses t[n % B]
    float vwf = ldf(Wf, lane & 15, fm) * 6.283185307179586f;
    float vbt = ldf(bt, lane & 31, fm);
    float xs[7];   // valid in lanes 0..31 (dup in 32..63)
#pragma unroll
    for (int k = 0; k < 7; ++k) {
        int ti = (base + k) % NB;
        float tv = ldf(tt, ti, fm);
        float pj = tv * vwf;
        float sv = sinf(pj), cv = cosf(pj);
        float remb = fmaxf((lane < 16) ? sv : cv, 0.f);   // relu(emb), emb=[sin|cos]
        float y0 = vbt, y1 = 0.f;
#pragma unroll 2
        for (int c = 0; c < 32; c += 2) {
            y0 = fmaf(bcast(remb, c    ), wbuf[4096 + (c    ) * 32 + (lane & 31)], y0);
            y1 = fmaf(bcast(remb, c + 1), wbuf[4096 + (c + 1) * 32 + (lane & 31)], y1);
        }
        xs[k] = fmaxf(y0 + y1, 0.f);
    }

    float pp[7], qq[7], xnew[7];

    // ---------------- Layer 1 ----------------
    __syncthreads();
    stage(w1a, 0, wbuf, 8192, fm);             // (128,64): rows 0..63 xi, 64..127 (xj-xi)
    __syncthreads();
    {
        float vb = ldf(b1a, lane, fm);
#pragma unroll
        for (int k = 0; k < 7; ++k) {
            float r0 = vb, r1 = 0.f, q0 = 0.f, q1 = 0.f;
#pragma unroll 2
            for (int c = 0; c < 64; c += 2) {
                float s0 = bcast(xh[k], c), s1 = bcast(xh[k], c + 1);
                r0 = fmaf(s0, wbuf[(c     ) * 64 + lane], r0);
                r1 = fmaf(s1, wbuf[(c + 1 ) * 64 + lane], r1);
                q0 = fmaf(s0, wbuf[(64 + c) * 64 + lane], q0);
                q1 = fmaf(s1, wbuf[(65 + c) * 64 + lane], q1);
            }
            qq[k] = q0 + q1;
            pp[k] = (r0 + r1) - qq[k];         // xi@Wtop + b - xi@Wbot
        }
    }
    __syncthreads();
    stage(w1b, 0, wbuf, 4096, fm);
    __syncthreads();
    {
        float vb = ldf(b1b, lane, fm);
#pragma unroll
        for (int i = 0; i < 7; ++i) {
            float mx = -3.0e38f;
#pragma unroll
            for (int jj = 0; jj < 6; ++jj) {
                int j = jj + (jj >= i);
                float hv = fmaxf(pp[i] + qq[j], 0.f);
                float y0 = vb, y1 = 0.f, y2 = 0.f, y3 = 0.f;
#pragma unroll 2
                for (int c = 0; c < 64; c += 4) {
                    y0 = fmaf(bcast(hv, c    ), wbuf[(c    ) * 64 + lane], y0);
                    y1 = fmaf(bcast(hv, c + 1), wbuf[(c + 1) * 64 + lane], y1);
                    y2 = fmaf(bcast(hv, c + 2), wbuf[(c + 2) * 64 + lane], y2);
                    y3 = fmaf(bcast(hv, c + 3), wbuf[(c + 3) * 64 + lane], y3);
                }
                mx = fmaxf(mx, (y0 + y1) + (y2 + y3));
            }
            xnew[i] = fmaxf(mx, 0.f);          // relu(edge_conv)
        }
#pragma unroll
        for (int k = 0; k < 7; ++k) xh[k] = xnew[k];
    }

    // ---------------- Layer 2 ---------------- input = [xh(64) | xs(32)]
    // w2a (192,64): rows 0..95 = x_i part (r), rows 96..191 = (x_j-x_i) part (q).
    // Staged in two 96-row chunks to keep LDS at 32 KB.
    __syncthreads();
    stage(w2a, 0, wbuf, 6144, fm);             // rows 0..95
    __syncthreads();
    {
        float vb = ldf(b2a, lane, fm);
#pragma unroll
        for (int k = 0; k < 7; ++k) {
            float r0 = vb, r1 = 0.f;
#pragma unroll 2
            for (int c = 0; c < 64; c += 2) {
                r0 = fmaf(bcast(xh[k], c    ), wbuf[(c    ) * 64 + lane], r0);
                r1 = fmaf(bcast(xh[k], c + 1), wbuf[(c + 1) * 64 + lane], r1);
            }
#pragma unroll 2
            for (int c = 0; c < 32; c += 2) {
                r0 = fmaf(bcast(xs[k], c    ), wbuf[(64 + c) * 64 + lane], r0);
                r1 = fmaf(bcast(xs[k], c + 1), wbuf[(65 + c) * 64 + lane], r1);
            }
            pp[k] = r0 + r1;                   // r so far
        }
    }
    __syncthreads();
    stage(w2a, 6144, wbuf, 6144, fm);          // rows 96..191
    __syncthreads();
    {
#pragma unroll
        for (int k = 0; k < 7; ++k) {
            float q0 = 0.f, q1 = 0.f;
#pragma unroll 2
            for (int c = 0; c < 64; c += 2) {
                q0 = fmaf(bcast(xh[k], c    ), wbuf[(c    ) * 64 + lane], q0);
                q1 = fmaf(bcast(xh[k], c + 1), wbuf[(c + 1) * 64 + lane], q1);
            }
#pragma unroll 2
            for (int c = 0; c < 32; c += 2) {
                q0 = fmaf(bcast(xs[k], c    ), wbuf[(64 + c) * 64 + lane], q0);
                q1 = fmaf(bcast(xs[k], c + 1), wbuf[(65 + c) * 64 + lane], q1);
            }
            qq[k] = q0 + q1;
            pp[k] -= qq[k];
        }
    }
    __syncthreads();
    stage(w2b, 0, wbuf, 4096, fm);
    __syncthreads();
    {
        float vb = ldf(b2b, lane, fm);
#pragma unroll
        for (int i = 0; i < 7; ++i) {
            float mx = -3.0e38f;
#pragma unroll
            for (int jj = 0; jj < 6; ++jj) {
                int j = jj + (jj >= i);
                float hv = fmaxf(pp[i] + qq[j], 0.f);
                float y0 = vb, y1 = 0.f, y2 = 0.f, y3 = 0.f;
#pragma unroll 2
                for (int c = 0; c < 64; c += 4) {
                    y0 = fmaf(bcast(hv, c    ), wbuf[(c    ) * 64 + lane], y0);
                    y1 = fmaf(bcast(hv, c + 1), wbuf[(c + 1) * 64 + lane], y1);
                    y2 = fmaf(bcast(hv, c + 2), wbuf[(c + 2) * 64 + lane], y2);
                    y3 = fmaf(bcast(hv, c + 3), wbuf[(c + 3) * 64 + lane], y3);
                }
                mx = fmaxf(mx, (y0 + y1) + (y2 + y3));
            }
            xnew[i] = fmaxf(mx, 0.f);
        }
#pragma unroll
        for (int k = 0; k < 7; ++k) xh[k] = xnew[k];
    }

    // ---------------- Layer 3 ---------------- out = edge_conv (no relu) / (std+1e-7)
    __syncthreads();
    stage(w3a, 0, wbuf, 6144, fm);             // rows 0..95
    __syncthreads();
    {
        float vb = ldf(b3a, lane, fm);
#pragma unroll
        for (int k = 0; k < 7; ++k) {
            float r0 = vb, r1 = 0.f;
#pragma unroll 2
            for (int c = 0; c < 64; c += 2) {
                r0 = fmaf(bcast(xh[k], c    ), wbuf[(c    ) * 64 + lane], r0);
                r1 = fmaf(bcast(xh[k], c + 1), wbuf[(c + 1) * 64 + lane], r1);
            }
#pragma unroll 2
            for (int c = 0; c < 32; c += 2) {
                r0 = fmaf(bcast(xs[k], c    ), wbuf[(64 + c) * 64 + lane], r0);
                r1 = fmaf(bcast(xs[k], c + 1), wbuf[(65 + c) * 64 + lane], r1);
            }
            pp[k] = r0 + r1;
        }
    }
    __syncthreads();
    stage(w3a, 6144, wbuf, 6144, fm);          // rows 96..191
    __syncthreads();
    {
#pragma unroll
        for (int k = 0; k < 7; ++k) {
            float q0 = 0.f, q1 = 0.f;
#pragma unroll 2
            for (int c = 0; c < 64; c += 2) {
                q0 = fmaf(bcast(xh[k], c    ), wbuf[(c    ) * 64 + lane], q0);
                q1 = fmaf(bcast(xh[k], c + 1), wbuf[(c + 1) * 64 + lane], q1);
            }
#pragma unroll 2
            for (int c = 0; c < 32; c += 2) {
                q0 = fmaf(bcast(xs[k], c    ), wbuf[(64 + c) * 64 + lane], q0);
                q1 = fmaf(bcast(xs[k], c + 1), wbuf[(65 + c) * 64 + lane], q1);
            }
            qq[k] = q0 + q1;
            pp[k] -= qq[k];
        }
    }
    // w3b (64,3) per-lane rows; second linear via per-lane product + wave reduce
    {
        float w3b0 = ldf(w3b, lane * 3, fm);
        float w3b1 = ldf(w3b, lane * 3 + 1, fm);
        float w3b2 = ldf(w3b, lane * 3 + 2, fm);
        float vb0 = ldf(b3b, 0, fm), vb1 = ldf(b3b, 1, fm), vb2 = ldf(b3b, 2, fm);

        // std uses t[n // 7] == t[g] (repeat_interleave)
        float tg = ldf(tt, g, fm);
        // std = sqrt((25^(2t)-1)/(2 ln 25)); 2*log2(25)=9.287712379549448, 1/(2 ln25)=0.15533740282828987
        float stdv = sqrtf((exp2f(tg * 9.287712379549448f) - 1.0f) * 0.15533740282828987f);
        float inv = 1.0f / (stdv + 1e-7f);

#pragma unroll
        for (int i = 0; i < 7; ++i) {
            float m0 = -3.0e38f, m1 = -3.0e38f, m2 = -3.0e38f;
#pragma unroll
            for (int jj = 0; jj < 6; ++jj) {
                int j = jj + (jj >= i);
                float hv = fmaxf(pp[i] + qq[j], 0.f);
                float s0 = hv * w3b0, s1 = hv * w3b1, s2 = hv * w3b2;
#pragma unroll
                for (int d = 1; d < 64; d <<= 1) {
                    s0 += __shfl_xor(s0, d, 64);
                    s1 += __shfl_xor(s1, d, 64);
                    s2 += __shfl_xor(s2, d, 64);
                }
                m0 = fmaxf(m0, s0); m1 = fmaxf(m1, s1); m2 = fmaxf(m2, s2);
            }
            m0 += vb0; m1 += vb1; m2 += vb2;
            if (lane < 3) {
                float v = ((lane == 0) ? m0 : (lane == 1) ? m1 : m2) * inv;
                int oi = (base + i) * 3 + lane;
                if (fm) ((float*)out)[oi] = v;
                else    ((u16*)out)[oi]  = f2b(v);
            }
        }
    }
}

extern "C" void kernel_launch(void* const* d_in, const int* in_sizes, int n_in,
                              void* d_out, int out_size, void* d_ws, size_t ws_size,
                              hipStream_t stream) {
    const void* omega = d_in[0];
    // d_in[1] = edge_index (structure is fixed fully-connected per graph; unused)
    const void* tt  = d_in[2];
    // d_in[3] = num_objs (== 7, hardcoded)
    const void* Wf  = d_in[4];
    const void* wi1 = d_in[5];
    const void* bi1 = d_in[6];
    const void* wi2 = d_in[7];
    const void* bi2 = d_in[8];
    const void* wt  = d_in[9];
    const void* bt  = d_in[10];
    const void* w1a = d_in[11];
    const void* b1a = d_in[12];
    const void* w1b = d_in[13];
    const void* b1b = d_in[14];
    const void* w2a = d_in[15];
    const void* b2a = d_in[16];
    const void* w2b = d_in[17];
    const void* b2b = d_in[18];
    const void* w3a = d_in[19];
    const void* b3a = d_in[20];
    const void* w3b = d_in[21];
    const void* b3b = d_in[22];

    int* flag = (int*)d_ws;
    detect_kernel<<<dim3(1), dim3(64), 0, stream>>>(tt, flag);
    gnn_kernel<<<dim3(12500), dim3(256), 0, stream>>>(
        omega, tt, Wf, wi1, bi1, wi2, bi2, wt, bt,
        w1a, b1a, w1b, b1b, w2a, b2a, w2b, b2b, w3a, b3a, w3b, b3b,
        d_out, flag);
}